// Round 6
// baseline (125.642 us; speedup 1.0000x reference)
//
#include <hip/hip_runtime.h>
#include <hip/hip_bf16.h>
#include <math.h>

// Problem constants
#define L_SEQ 4096
#define CDIM  512
#define NH    8
#define NKV   2
#define HD    64
#define EPS   1e-6f
// 1/sqrt(64) * log2(e), folded into Q at norm_rope so P = exp2(S) directly
#define QSCALE 0.18033688011f
#define NSPLIT 4
#define KVSPAN (L_SEQ / NSPLIT)

using short8 = __attribute__((ext_vector_type(8))) short;
using f32x4  = __attribute__((ext_vector_type(4))) float;
typedef unsigned short ushort_t;

// RNE float -> bf16 bits
__device__ __forceinline__ ushort_t f2bf(float f) {
    union { float f; unsigned u; } c; c.f = f;
    unsigned r = c.u + 0x7FFF + ((c.u >> 16) & 1);
    return (ushort_t)(r >> 16);
}
__device__ __forceinline__ float bf2f(ushort_t u) {
    union { unsigned u; float f; } c; c.u = ((unsigned)u) << 16;
    return c.f;
}

// async global->LDS, 16B per lane; LDS dest = wave-uniform base + lane*16
#define GLOAD_LDS16(g, l)                                                  \
    __builtin_amdgcn_global_load_lds(                                      \
        (const __attribute__((address_space(1))) unsigned int*)(g),        \
        (__attribute__((address_space(3))) unsigned int*)(l), 16, 0, 0)

// aligned LDS vector read (offsets are provably 16B-aligned)
__device__ __forceinline__ short8 lds_read8(const char* p) {
    return *reinterpret_cast<const short8*>(__builtin_assume_aligned(p, 16));
}

// ---------------------------------------------------------------------------
// f32 -> bf16 conversion for x and the 4 weights (one launch).
// ---------------------------------------------------------------------------
__global__ __launch_bounds__(256) void cvt_bf16(const float* __restrict__ x,
                                                const float* __restrict__ wq,
                                                const float* __restrict__ wk,
                                                const float* __restrict__ wv,
                                                const float* __restrict__ wo,
                                                ushort_t* __restrict__ xb,
                                                ushort_t* __restrict__ wqb,
                                                ushort_t* __restrict__ wkb,
                                                ushort_t* __restrict__ wvb,
                                                ushort_t* __restrict__ wob) {
    const size_t i = ((size_t)blockIdx.x * 256 + threadIdx.x) << 2;
    const float* s; ushort_t* d; size_t o;
    if (i < 2097152)      { s = x;  d = xb;  o = i; }
    else if (i < 2359296) { s = wq; d = wqb; o = i - 2097152; }
    else if (i < 2424832) { s = wk; d = wkb; o = i - 2359296; }
    else if (i < 2490368) { s = wv; d = wvb; o = i - 2424832; }
    else                  { s = wo; d = wob; o = i - 2490368; }
    const float4 v = *reinterpret_cast<const float4*>(s + o);
    ushort_t r[4] = { f2bf(v.x), f2bf(v.y), f2bf(v.z), f2bf(v.w) };
    *reinterpret_cast<uint2*>(d + o) = *reinterpret_cast<const uint2*>(r);
}

// ---------------------------------------------------------------------------
// bf16 MFMA NT GEMM: C[M][N] = A[M][K] * B[N][K]^T, fp32 accumulate.
// BM=BN=BK=64, 256 threads (2x2 waves, 32x32 per wave), double-buffered LDS.
// ---------------------------------------------------------------------------
template<bool OUT_BF16>
__global__ __launch_bounds__(256) void gemm_bf16_nt(const ushort_t* __restrict__ A,
                                                    const ushort_t* __restrict__ B,
                                                    void* __restrict__ Cv,
                                                    int M, int N, int K) {
    __shared__ short As[2][4096];   // [64 rows][64 k] bf16, 8KB each
    __shared__ short Bs[2][4096];

    const int tid = threadIdx.x;
    const int w = tid >> 6, lane = tid & 63;
    const int g = lane >> 4, r16 = lane & 15;
    const int wr = w >> 1, wc = w & 1;
    const int m0 = blockIdx.y * 64, n0 = blockIdx.x * 64;
    const int r7sw = (r16 & 7) << 4;

    const int lrow = lane >> 3;
    const int swzb = ((lane & 7) ^ lrow) << 4;
    const int c0 = w * 2, c1 = w * 2 + 1;
    const size_t rowK2 = (size_t)K * 2;

    const char* agA = (const char*)A + (size_t)(m0 + c0 * 8 + lrow) * rowK2 + swzb;
    const char* agB = agA + 8 * rowK2;
    const char* bgA = (const char*)B + (size_t)(n0 + c0 * 8 + lrow) * rowK2 + swzb;
    const char* bgB = bgA + 8 * rowK2;

    GLOAD_LDS16(agA, (char*)As[0] + c0 * 1024);
    GLOAD_LDS16(agB, (char*)As[0] + c1 * 1024);
    GLOAD_LDS16(bgA, (char*)Bs[0] + c0 * 1024);
    GLOAD_LDS16(bgB, (char*)Bs[0] + c1 * 1024);
    __syncthreads();

    f32x4 acc[2][2] = {};
    const int NKIT = K >> 6;
    int cur = 0;
    for (int it = 0; it < NKIT; ++it) {
        if (it + 1 < NKIT) {
            const size_t ko = (size_t)(it + 1) * 128;
            char* ad = (char*)As[cur ^ 1];
            char* bd = (char*)Bs[cur ^ 1];
            GLOAD_LDS16(agA + ko, ad + c0 * 1024);
            GLOAD_LDS16(agB + ko, ad + c1 * 1024);
            GLOAD_LDS16(bgA + ko, bd + c0 * 1024);
            GLOAD_LDS16(bgB + ko, bd + c1 * 1024);
        }
        const char* at = (const char*)As[cur];
        const char* bt = (const char*)Bs[cur];

        short8 af[2][2], bfr[2][2];
#pragma unroll
        for (int t = 0; t < 2; ++t)
#pragma unroll
            for (int ks = 0; ks < 2; ++ks) {
                af[t][ks]  = lds_read8(at + (wr * 32 + t * 16 + r16) * 128
                                          + ((ks * 64 + g * 16) ^ r7sw));
                bfr[t][ks] = lds_read8(bt + (wc * 32 + t * 16 + r16) * 128
                                          + ((ks * 64 + g * 16) ^ r7sw));
            }
        __builtin_amdgcn_s_setprio(1);
#pragma unroll
        for (int tm = 0; tm < 2; ++tm)
#pragma unroll
            for (int tn = 0; tn < 2; ++tn)
#pragma unroll
                for (int ks = 0; ks < 2; ++ks)
                    acc[tm][tn] = __builtin_amdgcn_mfma_f32_16x16x32_bf16(
                        af[tm][ks], bfr[tn][ks], acc[tm][tn], 0, 0, 0);
        __builtin_amdgcn_s_setprio(0);

        __syncthreads();
        cur ^= 1;
    }

#pragma unroll
    for (int tm = 0; tm < 2; ++tm)
#pragma unroll
        for (int tn = 0; tn < 2; ++tn)
#pragma unroll
            for (int jj = 0; jj < 4; ++jj) {
                const int row = m0 + wr * 32 + tm * 16 + g * 4 + jj;
                const int col = n0 + wc * 32 + tn * 16 + r16;
                if (OUT_BF16)
                    ((ushort_t*)Cv)[(size_t)row * N + col] = f2bf(acc[tm][tn][jj]);
                else
                    ((float*)Cv)[(size_t)row * N + col] = acc[tm][tn][jj];
            }
}

// ---------------------------------------------------------------------------
// Fused RMSNorm + RoPE, IN PLACE on bf16 q/k (Q pre-scaled by QSCALE).
// ---------------------------------------------------------------------------
__global__ __launch_bounds__(256) void norm_rope(ushort_t* __restrict__ q,
                                                 ushort_t* __restrict__ k,
                                                 const float* __restrict__ qw,
                                                 const float* __restrict__ kw) {
    const int wid  = threadIdx.x >> 6;
    const int lane = threadIdx.x & 63;
    const long row = (long)blockIdx.x * 4 + wid;
    const long QROWS = (long)L_SEQ * NH;

    ushort_t* ptr;
    const float* w;
    int pos;
    const bool isq = (row < QROWS);
    if (isq) {
        pos = (int)(row >> 3);
        ptr = q + (size_t)pos * (NH * HD) + (int)(row & 7) * HD;
        w = qw;
    } else {
        const long r = row - QROWS;
        pos = (int)(r >> 1);
        ptr = k + (size_t)pos * (NKV * HD) + (int)(r & 1) * HD;
        w = kw;
    }

    float x = bf2f(ptr[lane]);
    float ss = x * x;
#pragma unroll
    for (int off = 32; off; off >>= 1) ss += __shfl_xor(ss, off);
    float xn = x * rsqrtf(ss * (1.0f / 64.0f) + EPS) * w[lane];

    float xp = __shfl_xor(xn, 32);
    const int i = lane & 31;
    // inv_freq = 10000^(-i/32) = exp2(-i * log2(10000)/32)
    const float inv_freq = exp2f((float)i * -0.41524101186f);
    float s, c;
    sincosf((float)pos * inv_freq, &s, &c);
    float out = (lane < 32) ? (xn * c - xp * s) : (xn * c + xp * s);
    if (isq) out *= QSCALE;
    ptr[lane] = f2bf(out);
}

// ---------------------------------------------------------------------------
// Flash attention, bf16 MFMA 16x16x32, no-max softmax, split-KV x4.
// 4 waves/block, QR=32 q-rows per wave (2 row-tiles) -> each K/V fragment
// read feeds 2 MFMAs (halves LDS bytes/MFMA). 128 q-rows/block.
// Writes UNNORMALIZED partial O (bf16) + partial l (f32) per split.
// ---------------------------------------------------------------------------
__global__ __launch_bounds__(256) void attn_mfma(const ushort_t* __restrict__ qb,
                                                 const ushort_t* __restrict__ kb,
                                                 const ushort_t* __restrict__ vtb,
                                                 ushort_t* __restrict__ opart,
                                                 float* __restrict__ lpart) {
    __shared__ short Ks[2][4096];           // [64 kv][64 feat] bf16, dbuf
    __shared__ short Vs[2][4096];           // [64 feat][64 kv] bf16, dbuf
    __shared__ short Plds[4 * 32 * 64];     // per-wave P: 32 rows x 128B

    const int tid = threadIdx.x;
    const int w = tid >> 6, lane = tid & 63;
    const int g = lane >> 4, r16 = lane & 15;
    const int h = blockIdx.y, hkv = h >> 2;
    const int s = blockIdx.z;
    const int kvb = s * KVSPAN;
    const int qbase = blockIdx.x * 128 + w * 32;

    char* myP = reinterpret_cast<char*>(Plds) + w * 4096;
    const int r7sw = (r16 & 7) << 4;

    const int lrow = lane >> 3;
    const int swzb = ((lane & 7) ^ lrow) << 4;
    const int c0 = w * 2, c1 = w * 2 + 1;

    const char* kgA = (const char*)kb + (size_t)(kvb + c0 * 8 + lrow) * (NKV * HD * 2)
                      + hkv * (HD * 2) + swzb;
    const char* kgB = kgA + 8 * (NKV * HD * 2);
    const char* vgA = (const char*)vtb + (size_t)(hkv * HD + c0 * 8 + lrow) * (L_SEQ * 2)
                      + (size_t)kvb * 2 + swzb;
    const char* vgB = vgA + 8 * (size_t)(L_SEQ * 2);

    // Q fragments: row-tile m, row = qbase + m*16 + r16, k = ks*32 + g*8 + j
    short8 aq[2][2];
#pragma unroll
    for (int m = 0; m < 2; ++m)
#pragma unroll
        for (int ks = 0; ks < 2; ++ks)
            aq[m][ks] = *reinterpret_cast<const short8*>(
                &qb[(size_t)(qbase + m * 16 + r16) * CDIM + h * HD + ks * 32 + g * 8]);

    GLOAD_LDS16(kgA, (char*)Ks[0] + c0 * 1024);
    GLOAD_LDS16(kgB, (char*)Ks[0] + c1 * 1024);
    GLOAD_LDS16(vgA, (char*)Vs[0] + c0 * 1024);
    GLOAD_LDS16(vgB, (char*)Vs[0] + c1 * 1024);
    __syncthreads();

    f32x4 oacc[2][4] = {};
    float lsum[2][4] = {};

    int cur = 0;
    for (int it = 0; it < KVSPAN / 64; ++it) {
        if (it + 1 < KVSPAN / 64) {
            const size_t ko = (size_t)(it + 1) * 64 * (NKV * HD * 2);
            const size_t vo = (size_t)(it + 1) * 128;
            char* kd = (char*)Ks[cur ^ 1];
            char* vd = (char*)Vs[cur ^ 1];
            GLOAD_LDS16(kgA + ko, kd + c0 * 1024);
            GLOAD_LDS16(kgB + ko, kd + c1 * 1024);
            GLOAD_LDS16(vgA + vo, vd + c0 * 1024);
            GLOAD_LDS16(vgB + vo, vd + c1 * 1024);
        }

        const char* kt = (const char*)Ks[cur];
        const char* vt = (const char*)Vs[cur];

        // ---- S = Q K^T (16 MFMA, each bk read shared by 2 row-tiles)
        f32x4 sacc[2][4] = {};
        __builtin_amdgcn_s_setprio(1);
#pragma unroll
        for (int t = 0; t < 4; ++t) {
#pragma unroll
            for (int ks = 0; ks < 2; ++ks) {
                const short8 bk = lds_read8(
                    kt + (t * 16 + r16) * 128 + ((ks * 64 + g * 16) ^ r7sw));
                sacc[0][t] = __builtin_amdgcn_mfma_f32_16x16x32_bf16(aq[0][ks], bk, sacc[0][t], 0, 0, 0);
                sacc[1][t] = __builtin_amdgcn_mfma_f32_16x16x32_bf16(aq[1][ks], bk, sacc[1][t], 0, 0, 0);
            }
        }
        __builtin_amdgcn_s_setprio(0);

        // ---- P = exp2(S), accumulate l, pack to LDS (rows m*16 + g*4 + j)
#pragma unroll
        for (int m = 0; m < 2; ++m)
#pragma unroll
            for (int j = 0; j < 4; ++j) {
                const int row = m * 16 + g * 4 + j;
                char* rp = myP + row * 128;
                const int sw = (row & 7) << 4;
#pragma unroll
                for (int t = 0; t < 4; ++t) {
                    const float p = exp2f(sacc[m][t][j]);
                    lsum[m][j] += p;
                    *reinterpret_cast<short*>(rp + (((t * 16 + r16) * 2) ^ sw)) = (short)f2bf(p);
                }
            }

        // ---- O += P V (16 MFMA, each bv read shared by 2 row-tiles)
        __builtin_amdgcn_s_setprio(1);
#pragma unroll
        for (int ks = 0; ks < 2; ++ks) {
            const short8 ap0 = lds_read8(myP + (0 * 16 + r16) * 128 + ((ks * 64 + g * 16) ^ r7sw));
            const short8 ap1 = lds_read8(myP + (1 * 16 + r16) * 128 + ((ks * 64 + g * 16) ^ r7sw));
#pragma unroll
            for (int t = 0; t < 4; ++t) {
                const short8 bv = lds_read8(
                    vt + (t * 16 + r16) * 128 + ((ks * 64 + g * 16) ^ r7sw));
                oacc[0][t] = __builtin_amdgcn_mfma_f32_16x16x32_bf16(ap0, bv, oacc[0][t], 0, 0, 0);
                oacc[1][t] = __builtin_amdgcn_mfma_f32_16x16x32_bf16(ap1, bv, oacc[1][t], 0, 0, 0);
            }
        }
        __builtin_amdgcn_s_setprio(0);

        __syncthreads();
        cur ^= 1;
    }

    // ---- epilogue: reduce l over 16-lane group; store UNNORMALIZED O + l
    ushort_t* op = opart + (size_t)s * L_SEQ * CDIM;
    float* lp = lpart + (size_t)s * L_SEQ * NH;
#pragma unroll
    for (int m = 0; m < 2; ++m)
#pragma unroll
        for (int j = 0; j < 4; ++j) {
#pragma unroll
            for (int off = 1; off < 16; off <<= 1)
                lsum[m][j] += __shfl_xor(lsum[m][j], off);
            const int row = qbase + m * 16 + g * 4 + j;
#pragma unroll
            for (int t = 0; t < 4; ++t)
                op[(size_t)row * CDIM + h * HD + t * 16 + r16] = f2bf(oacc[m][t][j]);
            if (r16 == 0) lp[(size_t)row * NH + h] = lsum[m][j];
        }
}

// ---------------------------------------------------------------------------
// Combine 4 split-KV partials: out = sum(O_s) / sum(l_s), bf16.
// Writes IN PLACE over split 0 (each thread reads its bytes before writing).
// ---------------------------------------------------------------------------
__global__ __launch_bounds__(256) void combine_splits(const ushort_t* __restrict__ opart,
                                                      const float* __restrict__ lpart,
                                                      ushort_t* __restrict__ out) {
    const size_t i4 = ((size_t)blockIdx.x * 256 + threadIdx.x) << 2;
    const int row = (int)(i4 >> 9);
    const int h = (int)((i4 & 511) >> 6);
    float l = 0.0f;
#pragma unroll
    for (int s = 0; s < NSPLIT; ++s)
        l += lpart[(size_t)s * L_SEQ * NH + (size_t)row * NH + h];
    const float inv = 1.0f / l;

    float acc[4] = {};
#pragma unroll
    for (int s = 0; s < NSPLIT; ++s) {
        ushort_t a[4];
        *reinterpret_cast<uint2*>(a) =
            *reinterpret_cast<const uint2*>(opart + (size_t)s * L_SEQ * CDIM + i4);
#pragma unroll
        for (int j = 0; j < 4; ++j) acc[j] += bf2f(a[j]);
    }
    ushort_t r[4];
#pragma unroll
    for (int j = 0; j < 4; ++j) r[j] = f2bf(acc[j] * inv);
    *reinterpret_cast<uint2*>(out + i4) = *reinterpret_cast<const uint2*>(r);
}

// ---------------------------------------------------------------------------
extern "C" void kernel_launch(void* const* d_in, const int* in_sizes, int n_in,
                              void* d_out, int out_size, void* d_ws, size_t ws_size,
                              hipStream_t stream) {
    const float* x   = (const float*)d_in[0];   // [4096][512]
    const float* Wq  = (const float*)d_in[1];   // [512][512]
    const float* Wk  = (const float*)d_in[2];   // [128][512]
    const float* Wv  = (const float*)d_in[3];   // [128][512]
    const float* qnw = (const float*)d_in[4];   // [64]
    const float* knw = (const float*)d_in[5];   // [64]
    const float* Wo  = (const float*)d_in[6];   // [512][512]
    float* out = (float*)d_out;                 // [4096][512] f32

    // workspace layout (23.75 MB), phase-aliased:
    //   [0,16MB): opart[4][L][512] bf16. Split 0 doubles as xb (x bf16,
    //             dead before attn) and as abuf (combine writes in place).
    char* p = (char*)d_ws;
    ushort_t* opart = (ushort_t*)p;
    ushort_t* xb    = opart;                               // phase 1 alias
    ushort_t* abuf  = opart;                               // phase 3 alias
    ushort_t* qbuf  = (ushort_t*)(p + (16u << 20));        // 4 MB bf16 [L][512]
    ushort_t* kbuf  = (ushort_t*)(p + (20u << 20));        // 1 MB bf16 [L][128]
    ushort_t* vtb   = (ushort_t*)(p + (21u << 20));        // 1 MB bf16 [128][L]
    ushort_t* wqb   = (ushort_t*)(p + (22u << 20));        // 512 KB
    ushort_t* wkb   = wqb + (size_t)CDIM * CDIM;           // 128 KB
    ushort_t* wvb   = wkb + (size_t)NKV * HD * CDIM;       // 128 KB
    ushort_t* wob   = wvb + (size_t)NKV * HD * CDIM;       // 512 KB
    float*    lpart = (float*)(wob + (size_t)CDIM * CDIM); // 512 KB

    const dim3 blk(256);

    // f32 -> bf16 conversions (x + all weights)
    cvt_bf16<<<dim3(2688), blk, 0, stream>>>(x, Wq, Wk, Wv, Wo, xb, wqb, wkb, wvb, wob);

    // QKV projections (bf16 MFMA, bf16 out). V produced pre-transposed.
    gemm_bf16_nt<true><<<dim3(8, 64),  blk, 0, stream>>>(xb, wqb, qbuf, L_SEQ, CDIM, CDIM);
    gemm_bf16_nt<true><<<dim3(2, 64),  blk, 0, stream>>>(xb, wkb, kbuf, L_SEQ, NKV * HD, CDIM);
    gemm_bf16_nt<true><<<dim3(64, 2),  blk, 0, stream>>>(wvb, xb, vtb, NKV * HD, L_SEQ, CDIM);

    // RMSNorm + RoPE, in place on bf16 (Q pre-scaled by QSCALE)
    norm_rope<<<dim3((L_SEQ * (NH + NKV)) / 4), blk, 0, stream>>>(qbuf, kbuf, qnw, knw);

    // Attention: split-KV x4, QR=32 per wave, unnormalized partials
    attn_mfma<<<dim3(L_SEQ / 128, NH, NSPLIT), blk, 0, stream>>>(qbuf, kbuf, vtb, opart, lpart);

    // Combine partials -> bf16 attn out (in place over split 0)
    combine_splits<<<dim3((L_SEQ * CDIM) / (256 * 4)), blk, 0, stream>>>(opart, lpart, abuf);

    // Output projection (bf16 MFMA -> f32 out)
    gemm_bf16_nt<false><<<dim3(8, 64), blk, 0, stream>>>(abuf, wob, out, L_SEQ, CDIM, CDIM);
}

// Round 7
// 108.484 us; speedup vs baseline: 1.1582x; 1.1582x over previous
//
#include <hip/hip_runtime.h>
#include <hip/hip_bf16.h>
#include <math.h>

// Problem constants
#define L_SEQ 4096
#define CDIM  512
#define NH    8
#define NKV   2
#define HD    64
#define EPS   1e-6f
// 1/sqrt(64) * log2(e), folded into Q at norm_rope so P = exp2(S) directly
#define QSCALE 0.18033688011f
#define NSPLIT 4
#define KVSPAN (L_SEQ / NSPLIT)

using short8 = __attribute__((ext_vector_type(8))) short;
using f32x4  = __attribute__((ext_vector_type(4))) float;
using f32x16 = __attribute__((ext_vector_type(16))) float;
typedef unsigned short ushort_t;

// RNE float -> bf16 bits
__device__ __forceinline__ ushort_t f2bf(float f) {
    union { float f; unsigned u; } c; c.f = f;
    unsigned r = c.u + 0x7FFF + ((c.u >> 16) & 1);
    return (ushort_t)(r >> 16);
}
__device__ __forceinline__ float bf2f(ushort_t u) {
    union { unsigned u; float f; } c; c.u = ((unsigned)u) << 16;
    return c.f;
}

// async global->LDS, 16B per lane; LDS dest = wave-uniform base + lane*16
#define GLOAD_LDS16(g, l)                                                  \
    __builtin_amdgcn_global_load_lds(                                      \
        (const __attribute__((address_space(1))) unsigned int*)(g),        \
        (__attribute__((address_space(3))) unsigned int*)(l), 16, 0, 0)

// aligned LDS vector read (offsets are provably 16B-aligned)
__device__ __forceinline__ short8 lds_read8(const char* p) {
    return *reinterpret_cast<const short8*>(__builtin_assume_aligned(p, 16));
}

// pack two positive floats to one u32 of 2 bf16 (round-half-up): lo in low short
__device__ __forceinline__ unsigned pk_bf16(float lo, float hi) {
    const unsigned a = __float_as_uint(hi) + 0x8000u;
    const unsigned b = __float_as_uint(lo) + 0x8000u;
    return __builtin_amdgcn_perm(a, b, 0x07060302u);   // [hi.b3 hi.b2 lo.b3 lo.b2]
}

// ---------------------------------------------------------------------------
// f32 -> bf16 conversion for x and the 4 weights (one launch).
// ---------------------------------------------------------------------------
__global__ __launch_bounds__(256) void cvt_bf16(const float* __restrict__ x,
                                                const float* __restrict__ wq,
                                                const float* __restrict__ wk,
                                                const float* __restrict__ wv,
                                                const float* __restrict__ wo,
                                                ushort_t* __restrict__ xb,
                                                ushort_t* __restrict__ wqb,
                                                ushort_t* __restrict__ wkb,
                                                ushort_t* __restrict__ wvb,
                                                ushort_t* __restrict__ wob) {
    const size_t i = ((size_t)blockIdx.x * 256 + threadIdx.x) << 2;
    const float* s; ushort_t* d; size_t o;
    if (i < 2097152)      { s = x;  d = xb;  o = i; }
    else if (i < 2359296) { s = wq; d = wqb; o = i - 2097152; }
    else if (i < 2424832) { s = wk; d = wkb; o = i - 2359296; }
    else if (i < 2490368) { s = wv; d = wvb; o = i - 2424832; }
    else                  { s = wo; d = wob; o = i - 2490368; }
    const float4 v = *reinterpret_cast<const float4*>(s + o);
    ushort_t r[4] = { f2bf(v.x), f2bf(v.y), f2bf(v.z), f2bf(v.w) };
    *reinterpret_cast<uint2*>(d + o) = *reinterpret_cast<const uint2*>(r);
}

// ---------------------------------------------------------------------------
// bf16 MFMA NT GEMM: C[M][N] = A[M][K] * B[N][K]^T, fp32 accumulate.
// BM=BN=BK=64, 256 threads (2x2 waves, 32x32 per wave), double-buffered LDS.
// ---------------------------------------------------------------------------
template<bool OUT_BF16>
__global__ __launch_bounds__(256) void gemm_bf16_nt(const ushort_t* __restrict__ A,
                                                    const ushort_t* __restrict__ B,
                                                    void* __restrict__ Cv,
                                                    int M, int N, int K) {
    __shared__ short As[2][4096];   // [64 rows][64 k] bf16, 8KB each
    __shared__ short Bs[2][4096];

    const int tid = threadIdx.x;
    const int w = tid >> 6, lane = tid & 63;
    const int g = lane >> 4, r16 = lane & 15;
    const int wr = w >> 1, wc = w & 1;
    const int m0 = blockIdx.y * 64, n0 = blockIdx.x * 64;
    const int r7sw = (r16 & 7) << 4;

    const int lrow = lane >> 3;
    const int swzb = ((lane & 7) ^ lrow) << 4;
    const int c0 = w * 2, c1 = w * 2 + 1;
    const size_t rowK2 = (size_t)K * 2;

    const char* agA = (const char*)A + (size_t)(m0 + c0 * 8 + lrow) * rowK2 + swzb;
    const char* agB = agA + 8 * rowK2;
    const char* bgA = (const char*)B + (size_t)(n0 + c0 * 8 + lrow) * rowK2 + swzb;
    const char* bgB = bgA + 8 * rowK2;

    GLOAD_LDS16(agA, (char*)As[0] + c0 * 1024);
    GLOAD_LDS16(agB, (char*)As[0] + c1 * 1024);
    GLOAD_LDS16(bgA, (char*)Bs[0] + c0 * 1024);
    GLOAD_LDS16(bgB, (char*)Bs[0] + c1 * 1024);
    __syncthreads();

    f32x4 acc[2][2] = {};
    const int NKIT = K >> 6;
    int cur = 0;
    for (int it = 0; it < NKIT; ++it) {
        if (it + 1 < NKIT) {
            const size_t ko = (size_t)(it + 1) * 128;
            char* ad = (char*)As[cur ^ 1];
            char* bd = (char*)Bs[cur ^ 1];
            GLOAD_LDS16(agA + ko, ad + c0 * 1024);
            GLOAD_LDS16(agB + ko, ad + c1 * 1024);
            GLOAD_LDS16(bgA + ko, bd + c0 * 1024);
            GLOAD_LDS16(bgB + ko, bd + c1 * 1024);
        }
        const char* at = (const char*)As[cur];
        const char* bt = (const char*)Bs[cur];

        short8 af[2][2], bfr[2][2];
#pragma unroll
        for (int t = 0; t < 2; ++t)
#pragma unroll
            for (int ks = 0; ks < 2; ++ks) {
                af[t][ks]  = lds_read8(at + (wr * 32 + t * 16 + r16) * 128
                                          + ((ks * 64 + g * 16) ^ r7sw));
                bfr[t][ks] = lds_read8(bt + (wc * 32 + t * 16 + r16) * 128
                                          + ((ks * 64 + g * 16) ^ r7sw));
            }
        __builtin_amdgcn_s_setprio(1);
#pragma unroll
        for (int tm = 0; tm < 2; ++tm)
#pragma unroll
            for (int tn = 0; tn < 2; ++tn)
#pragma unroll
                for (int ks = 0; ks < 2; ++ks)
                    acc[tm][tn] = __builtin_amdgcn_mfma_f32_16x16x32_bf16(
                        af[tm][ks], bfr[tn][ks], acc[tm][tn], 0, 0, 0);
        __builtin_amdgcn_s_setprio(0);

        __syncthreads();
        cur ^= 1;
    }

#pragma unroll
    for (int tm = 0; tm < 2; ++tm)
#pragma unroll
        for (int tn = 0; tn < 2; ++tn)
#pragma unroll
            for (int jj = 0; jj < 4; ++jj) {
                const int row = m0 + wr * 32 + tm * 16 + g * 4 + jj;
                const int col = n0 + wc * 32 + tn * 16 + r16;
                if (OUT_BF16)
                    ((ushort_t*)Cv)[(size_t)row * N + col] = f2bf(acc[tm][tn][jj]);
                else
                    ((float*)Cv)[(size_t)row * N + col] = acc[tm][tn][jj];
            }
}

// ---------------------------------------------------------------------------
// Fused RMSNorm + RoPE, IN PLACE on bf16 q/k (Q pre-scaled by QSCALE).
// ---------------------------------------------------------------------------
__global__ __launch_bounds__(256) void norm_rope(ushort_t* __restrict__ q,
                                                 ushort_t* __restrict__ k,
                                                 const float* __restrict__ qw,
                                                 const float* __restrict__ kw) {
    const int wid  = threadIdx.x >> 6;
    const int lane = threadIdx.x & 63;
    const long row = (long)blockIdx.x * 4 + wid;
    const long QROWS = (long)L_SEQ * NH;

    ushort_t* ptr;
    const float* w;
    int pos;
    const bool isq = (row < QROWS);
    if (isq) {
        pos = (int)(row >> 3);
        ptr = q + (size_t)pos * (NH * HD) + (int)(row & 7) * HD;
        w = qw;
    } else {
        const long r = row - QROWS;
        pos = (int)(r >> 1);
        ptr = k + (size_t)pos * (NKV * HD) + (int)(r & 1) * HD;
        w = kw;
    }

    float x = bf2f(ptr[lane]);
    float ss = x * x;
#pragma unroll
    for (int off = 32; off; off >>= 1) ss += __shfl_xor(ss, off);
    float xn = x * rsqrtf(ss * (1.0f / 64.0f) + EPS) * w[lane];

    float xp = __shfl_xor(xn, 32);
    const int i = lane & 31;
    const float inv_freq = exp2f((float)i * -0.41524101186f);
    float s, c;
    sincosf((float)pos * inv_freq, &s, &c);
    float out = (lane < 32) ? (xn * c - xp * s) : (xn * c + xp * s);
    if (isq) out *= QSCALE;
    ptr[lane] = f2bf(out);
}

// ---------------------------------------------------------------------------
// Flash attention, 32x32x16 bf16 MFMA with SWAPPED QK^T (S^T = K x Q):
// each lane owns ONE q-row (lane&31); kv lives along accumulator registers,
// so softmax is lane-local (no cross-lane ops in the loop). P -> PV A-frag
// via shfl_xor(32) half-exchange, all in registers (no P LDS round-trip).
// 4 waves/block, 32 q-rows/wave, split-KV x4, no-max softmax.
// ---------------------------------------------------------------------------
__global__ __launch_bounds__(256, 3) void attn_mfma(const ushort_t* __restrict__ qb,
                                                    const ushort_t* __restrict__ kb,
                                                    const ushort_t* __restrict__ vtb,
                                                    ushort_t* __restrict__ opart,
                                                    float* __restrict__ lpart) {
    __shared__ short Ks[2][4096];           // [64 kv][64 feat] bf16, dbuf
    __shared__ short Vs[2][4096];           // [64 feat][64 kv] bf16, dbuf

    const int tid = threadIdx.x;
    const int w = tid >> 6, lane = tid & 63;
    const int l31 = lane & 31, hf = lane >> 5;
    const int h = blockIdx.y, hkv = h >> 2;
    const int s = blockIdx.z;
    const int kvb = s * KVSPAN;
    const int qw = blockIdx.x * 128 + w * 32;
    const int swz = (lane & 7) << 4;
    const bool lo = (hf == 0);

    // staging geometry (unchanged): wave w owns chunks c0,c1 (8 rows x 128B)
    const int lrow = lane >> 3;
    const int swzb = ((lane & 7) ^ lrow) << 4;
    const int c0 = w * 2, c1 = w * 2 + 1;

    const char* kgA = (const char*)kb + (size_t)(kvb + c0 * 8 + lrow) * (NKV * HD * 2)
                      + hkv * (HD * 2) + swzb;
    const char* kgB = kgA + 8 * (NKV * HD * 2);
    const char* vgA = (const char*)vtb + (size_t)(hkv * HD + c0 * 8 + lrow) * (L_SEQ * 2)
                      + (size_t)kvb * 2 + swzb;
    const char* vgB = vgA + 8 * (size_t)(L_SEQ * 2);

    // Q fragments (B operand of swapped QK^T): col = l31 = q-row,
    // k(d) = ks*16 + hf*8 + j  -> 16B contiguous loads.
    short8 qf[4];
#pragma unroll
    for (int ks = 0; ks < 4; ++ks)
        qf[ks] = *reinterpret_cast<const short8*>(
            &qb[(size_t)(qw + l31) * CDIM + h * HD + ks * 16 + hf * 8]);

    GLOAD_LDS16(kgA, (char*)Ks[0] + c0 * 1024);
    GLOAD_LDS16(kgB, (char*)Ks[0] + c1 * 1024);
    GLOAD_LDS16(vgA, (char*)Vs[0] + c0 * 1024);
    GLOAD_LDS16(vgB, (char*)Vs[0] + c1 * 1024);
    __syncthreads();

    f32x16 oacc[2] = {};
    float lsum = 0.0f;

    int cur = 0;
    for (int it = 0; it < KVSPAN / 64; ++it) {
        if (it + 1 < KVSPAN / 64) {
            const size_t ko = (size_t)(it + 1) * 64 * (NKV * HD * 2);
            const size_t vo = (size_t)(it + 1) * 128;
            char* kd = (char*)Ks[cur ^ 1];
            char* vd = (char*)Vs[cur ^ 1];
            GLOAD_LDS16(kgA + ko, kd + c0 * 1024);
            GLOAD_LDS16(kgB + ko, kd + c1 * 1024);
            GLOAD_LDS16(vgA + vo, vd + c0 * 1024);
            GLOAD_LDS16(vgB + vo, vd + c1 * 1024);
        }

        const char* kt = (const char*)Ks[cur];
        const char* vt = (const char*)Vs[cur];

        // ---- S^T = K Q (8 MFMA 32x32x16): A = K[kv32 x d16], B = Q[d16 x q32]
        f32x16 sacc[2] = {};
        __builtin_amdgcn_s_setprio(1);
#pragma unroll
        for (int sub = 0; sub < 2; ++sub) {
#pragma unroll
            for (int ks = 0; ks < 4; ++ks) {
                const short8 kf = lds_read8(
                    kt + (sub * 32 + l31) * 128 + ((ks * 32 + hf * 16) ^ swz));
                sacc[sub] = __builtin_amdgcn_mfma_f32_32x32x16_bf16(
                    kf, qf[ks], sacc[sub], 0, 0, 0);
            }
        }
        __builtin_amdgcn_s_setprio(0);

        // ---- P = exp2(S) lane-local; pack bf16 pairs (kv ascending per group)
        unsigned pkv[16];
#pragma unroll
        for (int sub = 0; sub < 2; ++sub) {
#pragma unroll
            for (int r2 = 0; r2 < 8; ++r2) {
                const float x = exp2f(sacc[sub][2 * r2]);
                const float y = exp2f(sacc[sub][2 * r2 + 1]);
                lsum += x + y;
                pkv[sub * 8 + r2] = pk_bf16(x, y);
            }
        }

        // ---- P -> A-fragments: half-exchange lane <-> lane^32.
        // frag kk (kv 16-chunk): lo lanes need [own.a, partner.a],
        // hi lanes need [partner.b, own.b]; a = pkv[kk*4+0..1], b = [+2..3].
        short8 pfrag[4];
#pragma unroll
        for (int kk = 0; kk < 4; ++kk) {
            const unsigned a0 = pkv[kk * 4 + 0], a1 = pkv[kk * 4 + 1];
            const unsigned b0 = pkv[kk * 4 + 2], b1 = pkv[kk * 4 + 3];
            const unsigned pa0 = __shfl_xor(a0, 32), pa1 = __shfl_xor(a1, 32);
            const unsigned pb0 = __shfl_xor(b0, 32), pb1 = __shfl_xor(b1, 32);
            union { unsigned u[4]; short8 s8; } pf;
            pf.u[0] = lo ? a0 : pb0;  pf.u[1] = lo ? a1 : pb1;
            pf.u[2] = lo ? pa0 : b0;  pf.u[3] = lo ? pa1 : b1;
            pfrag[kk] = pf.s8;
        }

        // ---- O += P V (8 MFMA): A = P[q32 x kv16], B = V[kv16 x d32]
        __builtin_amdgcn_s_setprio(1);
#pragma unroll
        for (int n = 0; n < 2; ++n) {
#pragma unroll
            for (int kk = 0; kk < 4; ++kk) {
                const short8 vf = lds_read8(
                    vt + (n * 32 + l31) * 128 + ((kk * 32 + hf * 16) ^ swz));
                oacc[n] = __builtin_amdgcn_mfma_f32_32x32x16_bf16(
                    pfrag[kk], vf, oacc[n], 0, 0, 0);
            }
        }
        __builtin_amdgcn_s_setprio(0);

        __syncthreads();
        cur ^= 1;
    }

    // ---- epilogue: fold lane-pair lsum; store UNNORMALIZED O (bf16) + l
    lsum += __shfl_xor(lsum, 32);
    ushort_t* op = opart + (size_t)s * L_SEQ * CDIM;
    float* lp = lpart + (size_t)s * L_SEQ * NH;
    if (lane < 32) lp[(size_t)(qw + lane) * NH + h] = lsum;
#pragma unroll
    for (int n = 0; n < 2; ++n)
#pragma unroll
        for (int r = 0; r < 16; ++r) {
            const int row = qw + (r & 3) + 8 * (r >> 2) + 4 * hf;
            const int col = h * HD + n * 32 + l31;
            op[(size_t)row * CDIM + col] = f2bf(oacc[n][r]);
        }
}

// ---------------------------------------------------------------------------
// Combine 4 split-KV partials: out = sum(O_s) / sum(l_s), bf16.
// Writes IN PLACE over split 0 (each thread reads its bytes before writing).
// ---------------------------------------------------------------------------
__global__ __launch_bounds__(256) void combine_splits(const ushort_t* __restrict__ opart,
                                                      const float* __restrict__ lpart,
                                                      ushort_t* __restrict__ out) {
    const size_t i4 = ((size_t)blockIdx.x * 256 + threadIdx.x) << 2;
    const int row = (int)(i4 >> 9);
    const int h = (int)((i4 & 511) >> 6);
    float l = 0.0f;
#pragma unroll
    for (int s = 0; s < NSPLIT; ++s)
        l += lpart[(size_t)s * L_SEQ * NH + (size_t)row * NH + h];
    const float inv = 1.0f / l;

    float acc[4] = {};
#pragma unroll
    for (int s = 0; s < NSPLIT; ++s) {
        ushort_t a[4];
        *reinterpret_cast<uint2*>(a) =
            *reinterpret_cast<const uint2*>(opart + (size_t)s * L_SEQ * CDIM + i4);
#pragma unroll
        for (int j = 0; j < 4; ++j) acc[j] += bf2f(a[j]);
    }
    ushort_t r[4];
#pragma unroll
    for (int j = 0; j < 4; ++j) r[j] = f2bf(acc[j] * inv);
    *reinterpret_cast<uint2*>(out + i4) = *reinterpret_cast<const uint2*>(r);
}

// ---------------------------------------------------------------------------
extern "C" void kernel_launch(void* const* d_in, const int* in_sizes, int n_in,
                              void* d_out, int out_size, void* d_ws, size_t ws_size,
                              hipStream_t stream) {
    const float* x   = (const float*)d_in[0];   // [4096][512]
    const float* Wq  = (const float*)d_in[1];   // [512][512]
    const float* Wk  = (const float*)d_in[2];   // [128][512]
    const float* Wv  = (const float*)d_in[3];   // [128][512]
    const float* qnw = (const float*)d_in[4];   // [64]
    const float* knw = (const float*)d_in[5];   // [64]
    const float* Wo  = (const float*)d_in[6];   // [512][512]
    float* out = (float*)d_out;                 // [4096][512] f32

    // workspace layout (23.75 MB), phase-aliased:
    //   [0,16MB): opart[4][L][512] bf16. Split 0 doubles as xb (x bf16,
    //             dead before attn) and as abuf (combine writes in place).
    char* p = (char*)d_ws;
    ushort_t* opart = (ushort_t*)p;
    ushort_t* xb    = opart;                               // phase 1 alias
    ushort_t* abuf  = opart;                               // phase 3 alias
    ushort_t* qbuf  = (ushort_t*)(p + (16u << 20));        // 4 MB bf16 [L][512]
    ushort_t* kbuf  = (ushort_t*)(p + (20u << 20));        // 1 MB bf16 [L][128]
    ushort_t* vtb   = (ushort_t*)(p + (21u << 20));        // 1 MB bf16 [128][L]
    ushort_t* wqb   = (ushort_t*)(p + (22u << 20));        // 512 KB
    ushort_t* wkb   = wqb + (size_t)CDIM * CDIM;           // 128 KB
    ushort_t* wvb   = wkb + (size_t)NKV * HD * CDIM;       // 128 KB
    ushort_t* wob   = wvb + (size_t)NKV * HD * CDIM;       // 512 KB
    float*    lpart = (float*)(wob + (size_t)CDIM * CDIM); // 512 KB

    const dim3 blk(256);

    // f32 -> bf16 conversions (x + all weights)
    cvt_bf16<<<dim3(2688), blk, 0, stream>>>(x, Wq, Wk, Wv, Wo, xb, wqb, wkb, wvb, wob);

    // QKV projections (bf16 MFMA, bf16 out). V produced pre-transposed.
    gemm_bf16_nt<true><<<dim3(8, 64),  blk, 0, stream>>>(xb, wqb, qbuf, L_SEQ, CDIM, CDIM);
    gemm_bf16_nt<true><<<dim3(2, 64),  blk, 0, stream>>>(xb, wkb, kbuf, L_SEQ, NKV * HD, CDIM);
    gemm_bf16_nt<true><<<dim3(64, 2),  blk, 0, stream>>>(wvb, xb, vtb, NKV * HD, L_SEQ, CDIM);

    // RMSNorm + RoPE, in place on bf16 (Q pre-scaled by QSCALE)
    norm_rope<<<dim3((L_SEQ * (NH + NKV)) / 4), blk, 0, stream>>>(qbuf, kbuf, qnw, knw);

    // Attention: split-KV x4, 32x32 swapped-QK^T, unnormalized partials
    attn_mfma<<<dim3(L_SEQ / 128, NH, NSPLIT), blk, 0, stream>>>(qbuf, kbuf, vtb, opart, lpart);

    // Combine partials -> bf16 attn out (in place over split 0)
    combine_splits<<<dim3((L_SEQ * CDIM) / (256 * 4)), blk, 0, stream>>>(opart, lpart, abuf);

    // Output projection (bf16 MFMA -> f32 out)
    gemm_bf16_nt<false><<<dim3(8, 64), blk, 0, stream>>>(abuf, wob, out, L_SEQ, CDIM, CDIM);
}